// Round 6
// baseline (293.968 us; speedup 1.0000x reference)
//
#include <hip/hip_runtime.h>
#include <hip/hip_bf16.h>
#include <cstdint>

// Problem constants
#define Bn   1024
#define Tn   128
#define En   300
#define Hn   100
#define Vn   50000
#define G4n  400   // 4*H
#define MPn  50048 // V padded to mult of 64
#define NPn  448   // 4H padded to mult of 16 (28 n-tiles; only 25 are real)
// gate-column PERMUTATION: jp = 4*u + q  <->  j = q*100 + u  (q = gate i,f,g,o)

typedef __bf16 bf16x8 __attribute__((ext_vector_type(8)));
typedef _Float16 half8 __attribute__((ext_vector_type(8)));
typedef _Float16 half2v __attribute__((ext_vector_type(2)));
typedef float  f32x4  __attribute__((ext_vector_type(4)));

// workspace byte offsets
#define OFF_TABLE  0ull         // f16 [Vn][448] permuted cols   44,800,000
#define OFF_WFRAG  44800000ull  // uint4 [28*4*64] W_hh B-frags     114,688
#define OFF_WFRAGB 44914688ull  // uint4 [10*28*64] W_ih B-frags    286,720
#define OFF_LLWT   45201408ull  // f32 [300][100] llW transposed    120,000
#define OFF_LV     45321408ull  // f32 [Bn][Hn]                     409,600
#define OFF_PN6    45731008ull  // f32 [Bn][6]                       24,576

// fast sigmoid/tanh: v_rcp_f32 (1 instr) instead of IEEE divide (~9 instr).
__device__ __forceinline__ float sigf(float x) {
    return __builtin_amdgcn_rcpf(1.0f + __expf(-x));
}
__device__ __forceinline__ float tanhfast(float x) {
    return 1.0f - 2.0f * __builtin_amdgcn_rcpf(__expf(2.0f * x) + 1.0f);
}

// LDS-only barrier: drain lgkmcnt but leave vmcnt free-running so the table
// gather prefetch stays in flight across the barrier.
#define BAR_LDS() do {                                         \
    asm volatile("s_waitcnt lgkmcnt(0)" ::: "memory");          \
    __builtin_amdgcn_s_barrier();                               \
    asm volatile("" ::: "memory");                              \
} while (0)

// VALU-pipe lane shift-down by N within each 16-lane row (0-fill past row end)
#define DPP_ADD_SHL(v, N) do {                                                     \
    int _s = __builtin_amdgcn_update_dpp(0, __builtin_bit_cast(int, (v)),          \
                                         0x100 | (N), 0xF, 0xF, true);             \
    (v) += __builtin_bit_cast(float, _s);                                          \
} while (0)

// -------- K0: W_hh -> f16 B-frags; W_ih -> bf16 B-frags; llW -> transposed ---
__global__ void k_prep(const float* __restrict__ W_ih, const float* __restrict__ W_hh,
                       const float* __restrict__ llW,
                       uint4* __restrict__ wfrag, uint4* __restrict__ wfragB,
                       float* __restrict__ llwt) {
    int idx = blockIdx.x * 256 + threadIdx.x;
    if (idx < 28 * 4 * 64) {  // W_hh frag: lane holds B[n=nt*16+(l&15)][k=kc*32+(l>>4)*8+j]
        int lane = idx & 63, tk = idx >> 6;
        int nt = tk >> 2, kc = tk & 3;
        int n = nt * 16 + (lane & 15);
        int k0 = kc * 32 + (lane >> 4) * 8;
        int q = n & 3, u = n >> 2;
        union { _Float16 h[8]; uint4 v; } pk;
#pragma unroll
        for (int j = 0; j < 8; j++) {
            int k = k0 + j;
            pk.h[j] = (_Float16)((u < Hn && k < Hn) ? W_hh[(size_t)(q * Hn + u) * Hn + k] : 0.0f);
        }
        wfrag[idx] = pk.v;
    }
    if (idx < 10 * 28 * 64) {  // W_ih frag (bf16): kc-major
        int lane = idx & 63, tk = idx >> 6;
        int kc = tk / 28, nsg = tk - kc * 28;
        int n = nsg * 16 + (lane & 15);
        int k0 = kc * 32 + (lane >> 4) * 8;
        int q = n & 3, u = n >> 2;
        union { __bf16 h[8]; uint4 v; } pk;
#pragma unroll
        for (int j = 0; j < 8; j++) {
            int k = k0 + j;
            pk.h[j] = (__bf16)((u < Hn && k < En) ? W_ih[(size_t)(q * Hn + u) * En + k] : 0.0f);
        }
        wfragB[idx] = pk.v;
    }
    if (idx < En * Hn) {  // llwt[k][h] = llW[h][k]
        int k = idx / Hn, h = idx - k * Hn;
        llwt[idx] = llW[(size_t)h * En + k];
    }
}

// -------- K1: table = emb @ W_ih^T + b (permuted cols, f16 out) --------------
__global__ __launch_bounds__(256, 2) void k_table(
    const float* __restrict__ emb, const uint4* __restrict__ wfragB,
    const float* __restrict__ b_ih, const float* __restrict__ b_hh,
    _Float16* __restrict__ table) {
    __shared__ __bf16 a_sh[64][328];   // 41,984 B (stride 328: rows offset 4 banks)
    const int tid = threadIdx.x;
    const int mt = blockIdx.x >> 1, nh = blockIdx.x & 1;

    // stage A: 64 rows x 320 cols (zeros past 300)
#pragma unroll
    for (int it = 0; it < 5; it++) {
        int x = it * 256 + tid;            // 0..1279
        int row = x / 20, seg = x - row * 20;
        int gr = mt * 64 + row;
        const float* ar = emb + (size_t)(gr < Vn ? gr : Vn - 1) * En;
        int c0 = seg * 16;
        union { __bf16 h[16]; bf16x8 v[2]; } pk;
#pragma unroll
        for (int g = 0; g < 4; g++) {
            int c = c0 + g * 4;
            if (c + 4 <= En) {
                float4 f = *(const float4*)(ar + c);
                pk.h[g * 4 + 0] = (__bf16)f.x; pk.h[g * 4 + 1] = (__bf16)f.y;
                pk.h[g * 4 + 2] = (__bf16)f.z; pk.h[g * 4 + 3] = (__bf16)f.w;
            } else {
                pk.h[g * 4 + 0] = (__bf16)0.f; pk.h[g * 4 + 1] = (__bf16)0.f;
                pk.h[g * 4 + 2] = (__bf16)0.f; pk.h[g * 4 + 3] = (__bf16)0.f;
            }
        }
        *(bf16x8*)&a_sh[row][c0] = pk.v[0];
        *(bf16x8*)&a_sh[row][c0 + 8] = pk.v[1];
    }
    __syncthreads();

    const int wv = tid >> 6, l = tid & 63;
    const int c16 = l & 15, quad = l >> 4;
    f32x4 acc[14];
#pragma unroll
    for (int i = 0; i < 14; i++) acc[i] = (f32x4){0.f, 0.f, 0.f, 0.f};

    uint4 bcur[14];
#pragma unroll
    for (int ns = 0; ns < 14; ns++) bcur[ns] = wfragB[((0 * 28 + nh * 14 + ns) << 6) + l];

    for (int kc = 0; kc < 10; kc++) {
        uint4 bnxt[14];
        if (kc < 9) {
#pragma unroll
            for (int ns = 0; ns < 14; ns++) bnxt[ns] = wfragB[(((kc + 1) * 28 + nh * 14 + ns) << 6) + l];
        }
        bf16x8 af = *(const bf16x8*)&a_sh[wv * 16 + c16][kc * 32 + quad * 8];
#pragma unroll
        for (int ns = 0; ns < 14; ns++)
            acc[ns] = __builtin_amdgcn_mfma_f32_16x16x32_bf16(af, __builtin_bit_cast(bf16x8, bcur[ns]), acc[ns], 0, 0, 0);
        if (kc < 9) {
#pragma unroll
            for (int ns = 0; ns < 14; ns++) bcur[ns] = bnxt[ns];
        }
    }
    // epilogue: C/D row = quad*4+r, col = c16
#pragma unroll
    for (int ns = 0; ns < 14; ns++) {
        int n = (nh * 14 + ns) * 16 + c16;
        int q = n & 3, u = n >> 2;
        if (u < Hn) {
            int j = q * Hn + u;
            float bias = b_ih[j] + b_hh[j];
#pragma unroll
            for (int r = 0; r < 4; r++) {
                int m = mt * 64 + wv * 16 + quad * 4 + r;
                if (m < Vn) table[(size_t)m * NPn + n] = (_Float16)(acc[ns][r] + bias);
            }
        }
    }
}

// -------- K2: label_vec = emb[lid] @ ll_W^T + ll_b (2-way K split) -----------
__global__ void k_label(const int* __restrict__ lwid, const float* __restrict__ emb,
                        const float* __restrict__ llwt, const float* __restrict__ llb,
                        float* __restrict__ lv) {
    __shared__ float er[En];
    __shared__ float part[Hn];
    int b = blockIdx.x;
    int lid = lwid[b];
    for (int k = threadIdx.x; k < En; k += 256) er[k] = emb[(size_t)lid * En + k];
    __syncthreads();
    int h = threadIdx.x & 127, half = threadIdx.x >> 7;
    float acc = 0.f;
    if (h < Hn) {
        int k0 = half * 150, k1 = k0 + 150;
        for (int k = k0; k < k1; k++) acc += er[k] * llwt[k * Hn + h];
        if (half == 1) part[h] = acc;
    }
    __syncthreads();
    if (h < Hn && half == 0) lv[(size_t)b * Hn + h] = acc + part[h] + llb[h];
}

// -------- K3: fused LSTM, 4 batch/block, 512 thr (8 waves), grid 256 ---------
// R6 structural change: R4's verified 4-batch M-row replication (A row r =
// h[batch r&3] -> every quad's C regs 0..3 = batches 0..3) combined with R5's
// proven 2-wave/SIMD overlap. The 25 REAL n-tiles (cols>=400 of NPn=448 are
// padding, never consumed -> dropped from MFMA) spread over 8 waves (w0: 4
// tiles, w1..w7: 3). Per SIMD: 24-28 MFMA/step for 4 batches vs R5's 56 for
// 4 -> MFMA issue halves. Each wave consumes ONLY its own tiles (gate buffer
// stays wave-synchronous, ONE barrier/step preserved). All state in LDS
// (~139 KB; 1 block/CU).
__global__ __launch_bounds__(512, 2) void k_lstm(
    const int* __restrict__ word_id, const int* __restrict__ sen_len,
    const _Float16* __restrict__ table, const uint4* __restrict__ wfrag,
    const float* __restrict__ lv, const float* __restrict__ linW,
    const float* __restrict__ linb, float* __restrict__ pn6,
    float* __restrict__ d_out) {
    __shared__ __align__(16) float    gbufs[8][320];      // per wave [4 mb][80] stride-5
    __shared__ __align__(16) _Float16 h_cur[2][4][144];   // [parity][mb][144], cols>=100 zero
    __shared__ __align__(16) _Float16 oh_lds[4][12832];   // [mb][t*100+u] (+32 pad)
    __shared__ __align__(16) float    spw[4][Tn][8];      // [mb][t][wave]
    __shared__ int      widc[4][Tn];                      // premultiplied wid*NPn
    __shared__ float    pos_sh[4][Hn];
    __shared__ float    lasth_sh[4][Hn];
    __shared__ float    neg_sh[4][Hn];
    __shared__ float    tk_val[4][4];
    __shared__ int      tk_idx[4][4];

    const int tid = threadIdx.x;
    const int w = tid >> 6, l = tid & 63;
    const int c16 = l & 15, quad = l >> 4;
    const int b0 = blockIdx.x * 4;

    // init: zero both h parities (incl. padding cols); stage word ids
    for (int i = tid; i < 576; i += 512) ((uint32_t*)h_cur)[i] = 0u;
    { int imb = tid >> 7, it = tid & 127; widc[imb][it] = word_id[(b0 + imb) * Tn + it] * NPn; }

    // wave tile assignment: w0 -> tiles 0..3 (u 0..15); w>=1 -> 3 tiles,
    // u = 16+12(w-1) .. +11. Covers u 0..99 exactly once.
    const bool has4 = (w == 0);
    const int TB = has4 ? 0 : 4 + 3 * (w - 1);
    const int UB = TB * 4;
    const int ITEMS = has4 ? 16 : 12;

    // persistent W_hh B-fragments (unified VGPR/AGPR file)
    half8 bfr[4][4];
#pragma unroll
    for (int kc = 0; kc < 4; kc++) {
        bfr[0][kc] = __builtin_bit_cast(half8, wfrag[((TB + 0) * 4 + kc) * 64 + l]);
        bfr[1][kc] = __builtin_bit_cast(half8, wfrag[((TB + 1) * 4 + kc) * 64 + l]);
        bfr[2][kc] = __builtin_bit_cast(half8, wfrag[((TB + 2) * 4 + kc) * 64 + l]);
        if (has4) bfr[3][kc] = __builtin_bit_cast(half8, wfrag[((TB + 3) * 4 + kc) * 64 + l]);
    }

    // lane work identity: one (u, batch) item per lane
    const int iu = l >> 2, mb = l & 3;
    const int u = UB + iu;                  // < 100 by construction when act
    const bool act = (iu < ITEMS);
    const int slen = act ? sen_len[b0 + mb] : 0;
    const float lt_reg = act ? lv[(size_t)(b0 + mb) * Hn + u] : 0.f;
    float* gb = &gbufs[w][0];
    const _Float16* tb_u = table + u * 4;

    __syncthreads();

    uint2 xq = {0, 0}, xq1 = {0, 0};
    if (act) {
        xq  = *(const uint2*)(tb_u + (size_t)widc[mb][0]);
        xq1 = *(const uint2*)(tb_u + (size_t)widc[mb][1]);
    }

    float c_reg = 0.f, sumh = 0.f, lasth = 0.f;
    float p_carry = 0.f;

    for (int t = 0; t < Tn; t++) {
        // ---- MFMA: gates[4 batches] = h . W_hh^T (A rows = h[batch r&3])
        const _Float16* hp = &h_cur[t & 1][0][0];
        f32x4 acc[4];
        {
            half8 af0 = *(const half8*)(hp + (c16 & 3) * 144 + quad * 8);
            acc[0] = __builtin_amdgcn_mfma_f32_16x16x32_f16(af0, bfr[0][0], (f32x4){0.f, 0.f, 0.f, 0.f}, 0, 0, 0);
            acc[1] = __builtin_amdgcn_mfma_f32_16x16x32_f16(af0, bfr[1][0], (f32x4){0.f, 0.f, 0.f, 0.f}, 0, 0, 0);
            acc[2] = __builtin_amdgcn_mfma_f32_16x16x32_f16(af0, bfr[2][0], (f32x4){0.f, 0.f, 0.f, 0.f}, 0, 0, 0);
            if (has4) acc[3] = __builtin_amdgcn_mfma_f32_16x16x32_f16(af0, bfr[3][0], (f32x4){0.f, 0.f, 0.f, 0.f}, 0, 0, 0);
        }
#pragma unroll
        for (int kc = 1; kc < 4; kc++) {
            half8 af = *(const half8*)(hp + (c16 & 3) * 144 + kc * 32 + quad * 8);
            acc[0] = __builtin_amdgcn_mfma_f32_16x16x32_f16(af, bfr[0][kc], acc[0], 0, 0, 0);
            acc[1] = __builtin_amdgcn_mfma_f32_16x16x32_f16(af, bfr[1][kc], acc[1], 0, 0, 0);
            acc[2] = __builtin_amdgcn_mfma_f32_16x16x32_f16(af, bfr[2][kc], acc[2], 0, 0, 0);
            if (has4) acc[3] = __builtin_amdgcn_mfma_f32_16x16x32_f16(af, bfr[3][kc], acc[3], 0, 0, 0);
        }
        // ---- gate stage: quad0 lanes write own tiles x 4 batches (stride-5)
        if (l < 16) {
            int adr0 = (c16 >> 2) * 5 + (c16 & 3);
#pragma unroll
            for (int r = 0; r < 4; r++) gb[r * 80 + adr0] = acc[0][r];
#pragma unroll
            for (int r = 0; r < 4; r++) gb[r * 80 + adr0 + 20] = acc[1][r];
#pragma unroll
            for (int r = 0; r < 4; r++) gb[r * 80 + adr0 + 40] = acc[2][r];
            if (has4) {
#pragma unroll
                for (int r = 0; r < 4; r++) gb[r * 80 + adr0 + 60] = acc[3][r];
            }
        }
        // ---- deferred score reduce for step t-1 (DPP rows + 2 shfl quads)
        {
            float pr = p_carry;
            DPP_ADD_SHL(pr, 4);
            DPP_ADD_SHL(pr, 8);
            pr += __shfl_down(pr, 32, 64);
            pr += __shfl_down(pr, 16, 64);
            if (l < 4 && t > 0) spw[l][t - 1][w] = pr;   // mb = l
        }
        // ---- consume (wave-synchronous vs own gate stage)
        float p = 0.f;
        if (act) {
            int base = mb * 80 + iu * 5;
            half2v x01 = __builtin_bit_cast(half2v, xq.x);
            half2v x23 = __builtin_bit_cast(half2v, xq.y);
            float gi = gb[base] + (float)x01.x;
            float gf = gb[base + 1] + (float)x01.y;
            float gg = gb[base + 2] + (float)x23.x;
            float go = gb[base + 3] + (float)x23.y;
            float c = sigf(gf) * c_reg + sigf(gi) * tanhfast(gg);
            c_reg = c;
            float hh = sigf(go) * tanhfast(c);
            _Float16 h16 = (_Float16)hh;
            h_cur[(t + 1) & 1][mb][u] = h16;
            oh_lds[mb][t * Hn + u] = h16;
            if (t < slen) sumh += hh;
            if (t == slen - 1) lasth = hh;
            p = hh * lt_reg;
            int tn2 = (t + 2 < Tn) ? t + 2 : Tn - 1;
            xq = xq1;
            xq1 = *(const uint2*)(tb_u + (size_t)widc[mb][tn2]);
        }
        p_carry = p;
        BAR_LDS();  // h(t+1) + spw visible to all waves; vmcnt stays free
    }
    // final deferred reduce for t = Tn-1
    {
        float pr = p_carry;
        DPP_ADD_SHL(pr, 4);
        DPP_ADD_SHL(pr, 8);
        pr += __shfl_down(pr, 32, 64);
        pr += __shfl_down(pr, 16, 64);
        if (l < 4) spw[l][Tn - 1][w] = pr;
    }
    __syncthreads();
    // ---- top-4: wave w<4 handles batch b0+w; tie-break smaller index
    if (w < 4) {
        int sl = sen_len[b0 + w];
        float4 a0 = *(const float4*)&spw[w][l][0];
        float4 a1 = *(const float4*)&spw[w][l][4];
        float4 c0 = *(const float4*)&spw[w][l + 64][0];
        float4 c1 = *(const float4*)&spw[w][l + 64][4];
        float sa = (a0.x + a0.y + a0.z + a0.w) + (a1.x + a1.y + a1.z + a1.w);
        float sb = (c0.x + c0.y + c0.z + c0.w) + (c1.x + c1.y + c1.z + c1.w);
        float s0 = (l < sl) ? sa : -1e30f;
        float s1 = (l + 64 < sl) ? sb : -1e30f;
        bool tk0 = false, tk1 = false;
#pragma unroll
        for (int p4 = 0; p4 < 4; p4++) {
            float v = tk0 ? -1e30f : s0;
            int ix = l;
            float v1 = tk1 ? -1e30f : s1;
            if (v1 > v) { v = v1; ix = l + 64; }
            for (int off = 32; off; off >>= 1) {
                float ov = __shfl_down(v, off, 64);
                int oi = __shfl_down(ix, off, 64);
                if (ov > v || (ov == v && oi < ix)) { v = ov; ix = oi; }
            }
            v = __shfl(v, 0, 64);
            ix = __shfl(ix, 0, 64);
            if (l == 0) { tk_val[w][p4] = v; tk_idx[w][p4] = ix; }
            if (ix == l) tk0 = true;
            if (ix == l + 64) tk1 = true;
        }
    }
    __syncthreads();
    // ---- pos / neg / lasth (one item per lane; gathers from LDS)
    if (act) {
        float pos = 0.f, nsum = sumh;
#pragma unroll
        for (int p4 = 0; p4 < 4; p4++) {
            int ix = tk_idx[mb][p4];
            float r = (float)oh_lds[mb][ix * Hn + u];
            pos += tk_val[mb][p4] * r;
            nsum -= r;
        }
        pos_sh[mb][u] = pos;
        lasth_sh[mb][u] = lasth;
        neg_sh[mb][u] = nsum;
    }
    __syncthreads();
    // ---- projections: out_f = lin(lasth), l_rep = lin(pos), pn6 = lin0(neg)
    if (tid < 72) {
        int which = tid / 24, r = tid - which * 24;
        int pmb = r / 6, o = r - pmb * 6;
        const float* src = (which == 0) ? &lasth_sh[pmb][0]
                         : (which == 1) ? &pos_sh[pmb][0] : &neg_sh[pmb][0];
        float acc2 = (which == 2) ? 0.f : linb[o];
        for (int uu = 0; uu < Hn; uu++) acc2 += src[uu] * linW[o * Hn + uu];
        if (which == 0)      d_out[(b0 + pmb) * 6 + o] = acc2;
        else if (which == 1) d_out[Bn * 6 + (b0 + pmb) * 6 + o] = acc2;
        else                 pn6[(b0 + pmb) * 6 + o] = acc2;  // bias added post-cumsum
    }
}

// -------- K4: r_rep = cumsum_b(pn6) + linb (wave-shuffle scan, writes d_out) -
__global__ __launch_bounds__(1024) void k_scan6(const float* __restrict__ pn6,
                                                const float* __restrict__ linb,
                                                float* __restrict__ d_out) {
    __shared__ float wsum[16];
    __shared__ float wpre[16];
    int o = blockIdx.x, t = threadIdx.x;
    int lane = t & 63, wv = t >> 6;
    float v = pn6[t * 6 + o];
#pragma unroll
    for (int off = 1; off < 64; off <<= 1) {
        float x = __shfl_up(v, off, 64);
        if (lane >= off) v += x;
    }
    if (lane == 63) wsum[wv] = v;
    __syncthreads();
    if (t < 16) {
        float s = wsum[t];
#pragma unroll
        for (int off = 1; off < 16; off <<= 1) {
            float x = __shfl_up(s, off, 64);
            if (t >= off) s += x;
        }
        wpre[t] = s;
    }
    __syncthreads();
    float pre = wv ? wpre[wv - 1] : 0.f;
    d_out[2 * Bn * 6 + t * 6 + o] = v + pre + linb[o];
}

extern "C" void kernel_launch(void* const* d_in, const int* in_sizes, int n_in,
                              void* d_out, int out_size, void* d_ws, size_t ws_size,
                              hipStream_t stream) {
    const int*   word_id = (const int*)d_in[0];
    const int*   sen_len = (const int*)d_in[1];
    const int*   lwid    = (const int*)d_in[2];
    const float* emb     = (const float*)d_in[3];
    const float* W_ih    = (const float*)d_in[4];
    const float* W_hh    = (const float*)d_in[5];
    const float* b_ih    = (const float*)d_in[6];
    const float* b_hh    = (const float*)d_in[7];
    const float* linW    = (const float*)d_in[8];
    const float* linb    = (const float*)d_in[9];
    const float* llW     = (const float*)d_in[10];
    const float* llb     = (const float*)d_in[11];

    char* ws = (char*)d_ws;
    _Float16* table  = (_Float16*)(ws + OFF_TABLE);
    uint4*    wfrag  = (uint4*)(ws + OFF_WFRAG);
    uint4*    wfragB = (uint4*)(ws + OFF_WFRAGB);
    float*    llwt   = (float*)(ws + OFF_LLWT);
    float*    lvp    = (float*)(ws + OFF_LV);
    float*    pn6    = (float*)(ws + OFF_PN6);
    float*    outp   = (float*)d_out;

    k_prep<<<118, 256, 0, stream>>>(W_ih, W_hh, llW, wfrag, wfragB, llwt);
    k_table<<<(MPn / 64) * 2, 256, 0, stream>>>(emb, wfragB, b_ih, b_hh, table);
    k_label<<<Bn, 256, 0, stream>>>(lwid, emb, llwt, llb, lvp);
    k_lstm<<<Bn / 4, 512, 0, stream>>>(word_id, sen_len, table, wfrag, lvp, linW, linb, pn6, outp);
    k_scan6<<<6, 1024, 0, stream>>>(pn6, linb, outp);
}

// Round 7
// 269.629 us; speedup vs baseline: 1.0903x; 1.0903x over previous
//
#include <hip/hip_runtime.h>
#include <hip/hip_bf16.h>
#include <cstdint>

// Problem constants
#define Bn   1024
#define Tn   128
#define En   300
#define Hn   100
#define Vn   50000
#define G4n  400   // 4*H
#define MPn  50048 // V padded to mult of 64
#define NPn  448   // 4H padded to mult of 16 (28 n-tiles; only 25 are real)
// gate-column PERMUTATION: jp = 4*u + q  <->  j = q*100 + u  (q = gate i,f,g,o)

typedef __bf16 bf16x8 __attribute__((ext_vector_type(8)));
typedef _Float16 half8 __attribute__((ext_vector_type(8)));
typedef _Float16 half2v __attribute__((ext_vector_type(2)));
typedef float  f32x4  __attribute__((ext_vector_type(4)));

// workspace byte offsets
#define OFF_TABLE  0ull         // f16 [Vn][448] permuted cols   44,800,000
#define OFF_WFRAG  44800000ull  // uint4 [28*4*64] W_hh B-frags     114,688
#define OFF_WFRAGB 44914688ull  // uint4 [10*28*64] W_ih B-frags    286,720
#define OFF_LLWT   45201408ull  // f32 [300][100] llW transposed    120,000
#define OFF_LV     45321408ull  // f32 [Bn][Hn]                     409,600
#define OFF_PN6    45731008ull  // f32 [Bn][6]                       24,576

// fast sigmoid/tanh: v_rcp_f32 (1 instr) instead of IEEE divide (~9 instr).
__device__ __forceinline__ float sigf(float x) {
    return __builtin_amdgcn_rcpf(1.0f + __expf(-x));
}
__device__ __forceinline__ float tanhfast(float x) {
    return 1.0f - 2.0f * __builtin_amdgcn_rcpf(__expf(2.0f * x) + 1.0f);
}

// LDS-only barrier: drain lgkmcnt but leave vmcnt free-running so the table
// gather prefetch stays in flight across the barrier.
#define BAR_LDS() do {                                         \
    asm volatile("s_waitcnt lgkmcnt(0)" ::: "memory");          \
    __builtin_amdgcn_s_barrier();                               \
    asm volatile("" ::: "memory");                              \
} while (0)

// -------- K0: W_hh -> f16 frags; W_ih -> bf16 B-frags; llW -> transposed -----
__global__ void k_prep(const float* __restrict__ W_ih, const float* __restrict__ W_hh,
                       const float* __restrict__ llW,
                       uint4* __restrict__ wfrag, uint4* __restrict__ wfragB,
                       float* __restrict__ llwt) {
    int idx = blockIdx.x * 256 + threadIdx.x;
    if (idx < 28 * 4 * 64) {  // lane holds W[n=nt*16+(l&15)][k=kc*32+(l>>4)*8+j]
        int lane = idx & 63, tk = idx >> 6;
        int nt = tk >> 2, kc = tk & 3;
        int n = nt * 16 + (lane & 15);
        int k0 = kc * 32 + (lane >> 4) * 8;
        int q = n & 3, u = n >> 2;
        union { _Float16 h[8]; uint4 v; } pk;
#pragma unroll
        for (int j = 0; j < 8; j++) {
            int k = k0 + j;
            pk.h[j] = (_Float16)((u < Hn && k < Hn) ? W_hh[(size_t)(q * Hn + u) * Hn + k] : 0.0f);
        }
        wfrag[idx] = pk.v;
    }
    if (idx < 10 * 28 * 64) {  // W_ih frag (bf16): kc-major
        int lane = idx & 63, tk = idx >> 6;
        int kc = tk / 28, nsg = tk - kc * 28;
        int n = nsg * 16 + (lane & 15);
        int k0 = kc * 32 + (lane >> 4) * 8;
        int q = n & 3, u = n >> 2;
        union { __bf16 h[8]; uint4 v; } pk;
#pragma unroll
        for (int j = 0; j < 8; j++) {
            int k = k0 + j;
            pk.h[j] = (__bf16)((u < Hn && k < En) ? W_ih[(size_t)(q * Hn + u) * En + k] : 0.0f);
        }
        wfragB[idx] = pk.v;
    }
    if (idx < En * Hn) {  // llwt[k][h] = llW[h][k]
        int k = idx / Hn, h = idx - k * Hn;
        llwt[idx] = llW[(size_t)h * En + k];
    }
}

// -------- K1: table = emb @ W_ih^T + b (permuted cols, f16 out) --------------
__global__ __launch_bounds__(256, 2) void k_table(
    const float* __restrict__ emb, const uint4* __restrict__ wfragB,
    const float* __restrict__ b_ih, const float* __restrict__ b_hh,
    _Float16* __restrict__ table) {
    __shared__ __bf16 a_sh[64][328];   // 41,984 B (stride 328: rows offset 4 banks)
    const int tid = threadIdx.x;
    const int mt = blockIdx.x >> 1, nh = blockIdx.x & 1;

    // stage A: 64 rows x 320 cols (zeros past 300)
#pragma unroll
    for (int it = 0; it < 5; it++) {
        int x = it * 256 + tid;            // 0..1279
        int row = x / 20, seg = x - row * 20;
        int gr = mt * 64 + row;
        const float* ar = emb + (size_t)(gr < Vn ? gr : Vn - 1) * En;
        int c0 = seg * 16;
        union { __bf16 h[16]; bf16x8 v[2]; } pk;
#pragma unroll
        for (int g = 0; g < 4; g++) {
            int c = c0 + g * 4;
            if (c + 4 <= En) {
                float4 f = *(const float4*)(ar + c);
                pk.h[g * 4 + 0] = (__bf16)f.x; pk.h[g * 4 + 1] = (__bf16)f.y;
                pk.h[g * 4 + 2] = (__bf16)f.z; pk.h[g * 4 + 3] = (__bf16)f.w;
            } else {
                pk.h[g * 4 + 0] = (__bf16)0.f; pk.h[g * 4 + 1] = (__bf16)0.f;
                pk.h[g * 4 + 2] = (__bf16)0.f; pk.h[g * 4 + 3] = (__bf16)0.f;
            }
        }
        *(bf16x8*)&a_sh[row][c0] = pk.v[0];
        *(bf16x8*)&a_sh[row][c0 + 8] = pk.v[1];
    }
    __syncthreads();

    const int wv = tid >> 6, l = tid & 63;
    const int c16 = l & 15, quad = l >> 4;
    f32x4 acc[14];
#pragma unroll
    for (int i = 0; i < 14; i++) acc[i] = (f32x4){0.f, 0.f, 0.f, 0.f};

    uint4 bcur[14];
#pragma unroll
    for (int ns = 0; ns < 14; ns++) bcur[ns] = wfragB[((0 * 28 + nh * 14 + ns) << 6) + l];

    for (int kc = 0; kc < 10; kc++) {
        uint4 bnxt[14];
        if (kc < 9) {
#pragma unroll
            for (int ns = 0; ns < 14; ns++) bnxt[ns] = wfragB[(((kc + 1) * 28 + nh * 14 + ns) << 6) + l];
        }
        bf16x8 af = *(const bf16x8*)&a_sh[wv * 16 + c16][kc * 32 + quad * 8];
#pragma unroll
        for (int ns = 0; ns < 14; ns++)
            acc[ns] = __builtin_amdgcn_mfma_f32_16x16x32_bf16(af, __builtin_bit_cast(bf16x8, bcur[ns]), acc[ns], 0, 0, 0);
        if (kc < 9) {
#pragma unroll
            for (int ns = 0; ns < 14; ns++) bcur[ns] = bnxt[ns];
        }
    }
    // epilogue: C/D row = quad*4+r, col = c16
#pragma unroll
    for (int ns = 0; ns < 14; ns++) {
        int n = (nh * 14 + ns) * 16 + c16;
        int q = n & 3, u = n >> 2;
        if (u < Hn) {
            int j = q * Hn + u;
            float bias = b_ih[j] + b_hh[j];
#pragma unroll
            for (int r = 0; r < 4; r++) {
                int m = mt * 64 + wv * 16 + quad * 4 + r;
                if (m < Vn) table[(size_t)m * NPn + n] = (_Float16)(acc[ns][r] + bias);
            }
        }
    }
}

// -------- K2: label_vec = emb[lid] @ ll_W^T + ll_b (2-way K split) -----------
__global__ void k_label(const int* __restrict__ lwid, const float* __restrict__ emb,
                        const float* __restrict__ llwt, const float* __restrict__ llb,
                        float* __restrict__ lv) {
    __shared__ float er[En];
    __shared__ float part[Hn];
    int b = blockIdx.x;
    int lid = lwid[b];
    for (int k = threadIdx.x; k < En; k += 256) er[k] = emb[(size_t)lid * En + k];
    __syncthreads();
    int h = threadIdx.x & 127, half = threadIdx.x >> 7;
    float acc = 0.f;
    if (h < Hn) {
        int k0 = half * 150, k1 = k0 + 150;
        for (int k = k0; k < k1; k++) acc += er[k] * llwt[k * Hn + h];
        if (half == 1) part[h] = acc;
    }
    __syncthreads();
    if (h < Hn && half == 0) lv[(size_t)b * Hn + h] = acc + part[h] + llb[h];
}

// -------- K3: fused LSTM, 4 batch/block, 8 waves, SWAPPED-OPERAND MFMA -------
// R7 key change: compute gates as D = W_hh . h (A = wfrag, B = h) instead of
// h . W_hh^T. Same wfrag data is a valid A-fragment; same h read is a valid
// B-fragment. Output D[row=n][col=batch]: with the permuted n=4u+q layout,
// lane (c16,quad) holds ALL FOUR GATES (acc regs r=0..3 = i,f,g,o) of
// u = (tile)*4+quad for batch c16&3 — the gate LDS round-trip (13-16
// ds_writes + lgkm wait + ds_read, ~240cy serial + bank conflicts) is GONE.
// Columns replicate 4x -> dup = c16>>2 selects which of the wave's tiles a
// lane consumes (explicit cndmask select; rule-#20 safe).
__global__ __launch_bounds__(512, 2) void k_lstm(
    const int* __restrict__ word_id, const int* __restrict__ sen_len,
    const _Float16* __restrict__ table, const uint4* __restrict__ wfrag,
    const float* __restrict__ lv, const float* __restrict__ linW,
    const float* __restrict__ linb, float* __restrict__ pn6,
    float* __restrict__ d_out) {
    __shared__ __align__(16) _Float16 h_cur[2][4][144];   // [parity][mb][144], cols>=100 zero
    __shared__ __align__(16) _Float16 oh_lds[4][12832];   // [mb][t*100+u] (+32 pad)
    __shared__ __align__(16) float    spw[4][Tn][8];      // [mb][t][wave]
    __shared__ int      widc[4][Tn];                      // premultiplied wid*NPn
    __shared__ float    pos_sh[4][Hn];
    __shared__ float    lasth_sh[4][Hn];
    __shared__ float    neg_sh[4][Hn];
    __shared__ float    tk_val[4][4];
    __shared__ int      tk_idx[4][4];

    const int tid = threadIdx.x;
    const int w = tid >> 6, l = tid & 63;
    const int c16 = l & 15, quad = l >> 4;
    const int b0 = blockIdx.x * 4;

    // init: zero both h parities (incl. padding cols); stage word ids
    for (int i = tid; i < 576; i += 512) ((uint32_t*)h_cur)[i] = 0u;
    { int imb = tid >> 7, it = tid & 127; widc[imb][it] = word_id[(b0 + imb) * Tn + it] * NPn; }

    // wave tile assignment over the 25 REAL tiles: w0 -> 4 tiles, w1..7 -> 3.
    const bool has4 = (w == 0);
    const int TB = has4 ? 0 : 4 + 3 * (w - 1);
    const int NT = has4 ? 4 : 3;

    // persistent W_hh fragments — now used as the A operand
    half8 bfr[4][4];
#pragma unroll
    for (int kc = 0; kc < 4; kc++) {
        bfr[0][kc] = __builtin_bit_cast(half8, wfrag[((TB + 0) * 4 + kc) * 64 + l]);
        bfr[1][kc] = __builtin_bit_cast(half8, wfrag[((TB + 1) * 4 + kc) * 64 + l]);
        bfr[2][kc] = __builtin_bit_cast(half8, wfrag[((TB + 2) * 4 + kc) * 64 + l]);
        if (has4) bfr[3][kc] = __builtin_bit_cast(half8, wfrag[((TB + 3) * 4 + kc) * 64 + l]);
    }

    // lane work identity: dup group selects the consumed tile
    const int mb = c16 & 3, dup = c16 >> 2;
    const bool act = (dup < NT);
    const int u = (TB + dup) * 4 + quad;     // <100 whenever act
    const int slen = act ? sen_len[b0 + mb] : 0;
    const float lt_reg = act ? lv[(size_t)(b0 + mb) * Hn + u] : 0.f;
    const _Float16* tb_u = table + u * 4;

    __syncthreads();

    uint2 xq = {0, 0}, xq1 = {0, 0};
    if (act) {
        xq  = *(const uint2*)(tb_u + (size_t)widc[mb][0]);
        xq1 = *(const uint2*)(tb_u + (size_t)widc[mb][1]);
    }

    float c_reg = 0.f, sumh = 0.f, lasth = 0.f;
    float p_carry = 0.f;

    for (int t = 0; t < Tn; t++) {
        // ---- B-fragments: h for batch c16&3 (identical read to before)
        const _Float16* hp = &h_cur[t & 1][0][0];
        half8 hf0 = *(const half8*)(hp + (c16 & 3) * 144 + 0 * 32 + quad * 8);
        half8 hf1 = *(const half8*)(hp + (c16 & 3) * 144 + 1 * 32 + quad * 8);
        half8 hf2 = *(const half8*)(hp + (c16 & 3) * 144 + 2 * 32 + quad * 8);
        half8 hf3 = *(const half8*)(hp + (c16 & 3) * 144 + 3 * 32 + quad * 8);
        // ---- MFMA: D = W_hh . h  (A = bfr, B = hf) — gates land lane-local
        f32x4 acc0, acc1, acc2, acc3;
        acc0 = __builtin_amdgcn_mfma_f32_16x16x32_f16(bfr[0][0], hf0, (f32x4){0.f, 0.f, 0.f, 0.f}, 0, 0, 0);
        acc1 = __builtin_amdgcn_mfma_f32_16x16x32_f16(bfr[1][0], hf0, (f32x4){0.f, 0.f, 0.f, 0.f}, 0, 0, 0);
        acc2 = __builtin_amdgcn_mfma_f32_16x16x32_f16(bfr[2][0], hf0, (f32x4){0.f, 0.f, 0.f, 0.f}, 0, 0, 0);
        if (has4) acc3 = __builtin_amdgcn_mfma_f32_16x16x32_f16(bfr[3][0], hf0, (f32x4){0.f, 0.f, 0.f, 0.f}, 0, 0, 0);
        acc0 = __builtin_amdgcn_mfma_f32_16x16x32_f16(bfr[0][1], hf1, acc0, 0, 0, 0);
        acc1 = __builtin_amdgcn_mfma_f32_16x16x32_f16(bfr[1][1], hf1, acc1, 0, 0, 0);
        acc2 = __builtin_amdgcn_mfma_f32_16x16x32_f16(bfr[2][1], hf1, acc2, 0, 0, 0);
        if (has4) acc3 = __builtin_amdgcn_mfma_f32_16x16x32_f16(bfr[3][1], hf1, acc3, 0, 0, 0);
        acc0 = __builtin_amdgcn_mfma_f32_16x16x32_f16(bfr[0][2], hf2, acc0, 0, 0, 0);
        acc1 = __builtin_amdgcn_mfma_f32_16x16x32_f16(bfr[1][2], hf2, acc1, 0, 0, 0);
        acc2 = __builtin_amdgcn_mfma_f32_16x16x32_f16(bfr[2][2], hf2, acc2, 0, 0, 0);
        if (has4) acc3 = __builtin_amdgcn_mfma_f32_16x16x32_f16(bfr[3][2], hf2, acc3, 0, 0, 0);
        acc0 = __builtin_amdgcn_mfma_f32_16x16x32_f16(bfr[0][3], hf3, acc0, 0, 0, 0);
        acc1 = __builtin_amdgcn_mfma_f32_16x16x32_f16(bfr[1][3], hf3, acc1, 0, 0, 0);
        acc2 = __builtin_amdgcn_mfma_f32_16x16x32_f16(bfr[2][3], hf3, acc2, 0, 0, 0);
        if (has4) acc3 = __builtin_amdgcn_mfma_f32_16x16x32_f16(bfr[3][3], hf3, acc3, 0, 0, 0);
        // ---- deferred score reduce for step t-1 (overlaps MFMA latency)
        {
            float pr = p_carry;
            pr += __shfl_xor(pr, 4, 64);
            pr += __shfl_xor(pr, 8, 64);
            pr += __shfl_xor(pr, 16, 64);
            pr += __shfl_xor(pr, 32, 64);
            if (l < 4 && t > 0) spw[l][t - 1][w] = pr;   // l = mb
        }
        // ---- select this lane's tile (dup) — explicit cndmask, no indexing
        f32x4 g = acc0;
        g = (dup == 1) ? acc1 : g;
        g = (dup == 2) ? acc2 : g;
        if (has4) g = (dup == 3) ? acc3 : g;
        // ---- gates -> h (acc regs r=0..3 are i,f,g,o for this lane's u)
        float p = 0.f;
        if (act) {
            half2v x01 = __builtin_bit_cast(half2v, xq.x);
            half2v x23 = __builtin_bit_cast(half2v, xq.y);
            float gi = g[0] + (float)x01.x;
            float gf = g[1] + (float)x01.y;
            float gg = g[2] + (float)x23.x;
            float go = g[3] + (float)x23.y;
            float c = sigf(gf) * c_reg + sigf(gi) * tanhfast(gg);
            c_reg = c;
            float hh = sigf(go) * tanhfast(c);
            _Float16 h16 = (_Float16)hh;
            h_cur[(t + 1) & 1][mb][u] = h16;
            oh_lds[mb][t * Hn + u] = h16;
            if (t < slen) sumh += hh;
            if (t == slen - 1) lasth = hh;
            p = hh * lt_reg;
            int tn2 = (t + 2 < Tn) ? t + 2 : Tn - 1;
            xq = xq1;
            xq1 = *(const uint2*)(tb_u + (size_t)widc[mb][tn2]);
        }
        p_carry = p;
        BAR_LDS();  // h(t+1) + spw visible to all waves; vmcnt stays free
    }
    // final deferred reduce for t = Tn-1
    {
        float pr = p_carry;
        pr += __shfl_xor(pr, 4, 64);
        pr += __shfl_xor(pr, 8, 64);
        pr += __shfl_xor(pr, 16, 64);
        pr += __shfl_xor(pr, 32, 64);
        if (l < 4) spw[l][Tn - 1][w] = pr;
    }
    __syncthreads();
    // ---- top-4: wave w<4 handles batch b0+w; tie-break smaller index
    if (w < 4) {
        int sl = sen_len[b0 + w];
        float4 a0 = *(const float4*)&spw[w][l][0];
        float4 a1 = *(const float4*)&spw[w][l][4];
        float4 c0 = *(const float4*)&spw[w][l + 64][0];
        float4 c1 = *(const float4*)&spw[w][l + 64][4];
        float sa = (a0.x + a0.y + a0.z + a0.w) + (a1.x + a1.y + a1.z + a1.w);
        float sb = (c0.x + c0.y + c0.z + c0.w) + (c1.x + c1.y + c1.z + c1.w);
        float s0 = (l < sl) ? sa : -1e30f;
        float s1 = (l + 64 < sl) ? sb : -1e30f;
        bool tk0 = false, tk1 = false;
#pragma unroll
        for (int p4 = 0; p4 < 4; p4++) {
            float v = tk0 ? -1e30f : s0;
            int ix = l;
            float v1 = tk1 ? -1e30f : s1;
            if (v1 > v) { v = v1; ix = l + 64; }
            for (int off = 32; off; off >>= 1) {
                float ov = __shfl_down(v, off, 64);
                int oi = __shfl_down(ix, off, 64);
                if (ov > v || (ov == v && oi < ix)) { v = ov; ix = oi; }
            }
            v = __shfl(v, 0, 64);
            ix = __shfl(ix, 0, 64);
            if (l == 0) { tk_val[w][p4] = v; tk_idx[w][p4] = ix; }
            if (ix == l) tk0 = true;
            if (ix == l + 64) tk1 = true;
        }
    }
    __syncthreads();
    // ---- pos / neg / lasth (one item per lane; gathers from LDS)
    if (act) {
        float pos = 0.f, nsum = sumh;
#pragma unroll
        for (int p4 = 0; p4 < 4; p4++) {
            int ix = tk_idx[mb][p4];
            float r = (float)oh_lds[mb][ix * Hn + u];
            pos += tk_val[mb][p4] * r;
            nsum -= r;
        }
        pos_sh[mb][u] = pos;
        lasth_sh[mb][u] = lasth;
        neg_sh[mb][u] = nsum;
    }
    __syncthreads();
    // ---- projections: out_f = lin(lasth), l_rep = lin(pos), pn6 = lin0(neg)
    if (tid < 72) {
        int which = tid / 24, r = tid - which * 24;
        int pmb = r / 6, o = r - pmb * 6;
        const float* src = (which == 0) ? &lasth_sh[pmb][0]
                         : (which == 1) ? &pos_sh[pmb][0] : &neg_sh[pmb][0];
        float acc2 = (which == 2) ? 0.f : linb[o];
        for (int uu = 0; uu < Hn; uu++) acc2 += src[uu] * linW[o * Hn + uu];
        if (which == 0)      d_out[(b0 + pmb) * 6 + o] = acc2;
        else if (which == 1) d_out[Bn * 6 + (b0 + pmb) * 6 + o] = acc2;
        else                 pn6[(b0 + pmb) * 6 + o] = acc2;  // bias added post-cumsum
    }
}

// -------- K4: r_rep = cumsum_b(pn6) + linb (wave-shuffle scan, writes d_out) -
__global__ __launch_bounds__(1024) void k_scan6(const float* __restrict__ pn6,
                                                const float* __restrict__ linb,
                                                float* __restrict__ d_out) {
    __shared__ float wsum[16];
    __shared__ float wpre[16];
    int o = blockIdx.x, t = threadIdx.x;
    int lane = t & 63, wv = t >> 6;
    float v = pn6[t * 6 + o];
#pragma unroll
    for (int off = 1; off < 64; off <<= 1) {
        float x = __shfl_up(v, off, 64);
        if (lane >= off) v += x;
    }
    if (lane == 63) wsum[wv] = v;
    __syncthreads();
    if (t < 16) {
        float s = wsum[t];
#pragma unroll
        for (int off = 1; off < 16; off <<= 1) {
            float x = __shfl_up(s, off, 64);
            if (t >= off) s += x;
        }
        wpre[t] = s;
    }
    __syncthreads();
    float pre = wv ? wpre[wv - 1] : 0.f;
    d_out[2 * Bn * 6 + t * 6 + o] = v + pre + linb[o];
}

extern "C" void kernel_launch(void* const* d_in, const int* in_sizes, int n_in,
                              void* d_out, int out_size, void* d_ws, size_t ws_size,
                              hipStream_t stream) {
    const int*   word_id = (const int*)d_in[0];
    const int*   sen_len = (const int*)d_in[1];
    const int*   lwid    = (const int*)d_in[2];
    const float* emb     = (const float*)d_in[3];
    const float* W_ih    = (const float*)d_in[4];
    const float* W_hh    = (const float*)d_in[5];
    const float* b_ih    = (const float*)d_in[6];
    const float* b_hh    = (const float*)d_in[7];
    const float* linW    = (const float*)d_in[8];
    const float* linb    = (const float*)d_in[9];
    const float* llW     = (const float*)d_in[10];
    const float* llb     = (const float*)d_in[11];

    char* ws = (char*)d_ws;
    _Float16* table  = (_Float16*)(ws + OFF_TABLE);
    uint4*    wfrag  = (uint4*)(ws + OFF_WFRAG);
    uint4*    wfragB = (uint4*)(ws + OFF_WFRAGB);
    float*    llwt   = (float*)(ws + OFF_LLWT);
    float*    lvp    = (float*)(ws + OFF_LV);
    float*    pn6    = (float*)(ws + OFF_PN6);
    float*    outp   = (float*)d_out;

    k_prep<<<118, 256, 0, stream>>>(W_ih, W_hh, llW, wfrag, wfragB, llwt);
    k_table<<<(MPn / 64) * 2, 256, 0, stream>>>(emb, wfragB, b_ih, b_hh, table);
    k_label<<<Bn, 256, 0, stream>>>(lwid, emb, llwt, llb, lvp);
    k_lstm<<<Bn / 4, 512, 0, stream>>>(word_id, sen_len, table, wfrag, lvp, linW, linb, pn6, outp);
    k_scan6<<<6, 1024, 0, stream>>>(pn6, linb, outp);
}